// Round 1
// baseline (538.065 us; speedup 1.0000x reference)
//
#include <hip/hip_runtime.h>
#include <hip/hip_bf16.h>

#define BATCH 4
#define HH 128
#define WW 128
#define CE 32
#define CF 64
#define CIN 96
#define KK 9
#define COM 27   // 18 offset + 9 mask channels
#define COUT 64
#define TPB 64   // pixels per block in deform kernel

// ---- workspace layout (float element offsets) ----
#define OX_OFF 0
#define OX_SZ (BATCH*HH*WW*CIN)            // 6,291,456
#define OM_OFF (OX_OFF + OX_SZ)
#define OM_SZ (BATCH*HH*WW*COM)            // 1,769,472
#define WC_OFF (OM_OFF + OM_SZ)
#define WC_SZ (KK*CIN*COM)                 // 23,328
#define WK_OFF (WC_OFF + WC_SZ)
#define WK_SZ (KK*CIN*COUT)                // 55,296

// Repack weights:
//   wcomb[tap][c][oc27]  (oc<18: offset conv, oc>=18: mask conv)
//   wkt[k][c][oc64]      (deform regression weights)
__global__ void prep_weights(const float* __restrict__ off_w,
                             const float* __restrict__ mod_w,
                             const float* __restrict__ reg_w,
                             float* __restrict__ ws) {
  float* wcomb = ws + WC_OFF;
  float* wkt   = ws + WK_OFF;
  int idx = blockIdx.x * blockDim.x + threadIdx.x;
  int total = WC_SZ + WK_SZ;
  for (int e = idx; e < total; e += gridDim.x * blockDim.x) {
    if (e < WC_SZ) {
      int oc  = e % COM;
      int c   = (e / COM) % CIN;
      int tap = e / (COM * CIN);
      float v;
      if (oc < 18) v = off_w[(oc * CIN + c) * KK + tap];
      else         v = mod_w[((oc - 18) * CIN + c) * KK + tap];
      wcomb[e] = v;
    } else {
      int e2 = e - WC_SZ;
      int oc = e2 % COUT;
      int c  = (e2 / COUT) % CIN;
      int k  = e2 / (COUT * CIN);
      wkt[e2] = reg_w[(oc * CIN + c) * KK + k];
    }
  }
}

// Fused LN(evt) + LN(efnet) + concat -> ox in NHWC [B][H][W][96]
__global__ __launch_bounds__(128) void ln_concat(
    const float* __restrict__ evt, const float* __restrict__ efn,
    const float* __restrict__ w_e, const float* __restrict__ b_e,
    const float* __restrict__ w_f, const float* __restrict__ b_f,
    float* __restrict__ ox) {
  __shared__ float vals[WW * 97];           // padded stride 97 (bank-conflict-free)
  __shared__ float mu_e[WW], rs_e[WW], mu_f[WW], rs_f[WW];
  __shared__ float lnw[CIN], lnb[CIN];
  int t = threadIdx.x;
  int b = blockIdx.x / HH, y = blockIdx.x % HH;
  if (t < CIN) {
    lnw[t] = (t < CE) ? w_e[t] : w_f[t - CE];
    lnb[t] = (t < CE) ? b_e[t] : b_f[t - CE];
  }
  int x = t;
  float s = 0.f, s2 = 0.f;
  const float* pe = evt + ((size_t)(b * CE) * HH + y) * WW + x;
  for (int c = 0; c < CE; ++c) {
    float v = pe[(size_t)c * HH * WW];
    vals[x * 97 + c] = v;
    s += v; s2 += v * v;
  }
  float mu = s * (1.f / CE);
  float var = s2 * (1.f / CE) - mu * mu;
  mu_e[x] = mu; rs_e[x] = rsqrtf(var + 1e-5f);
  s = 0.f; s2 = 0.f;
  const float* pf = efn + ((size_t)(b * CF) * HH + y) * WW + x;
  for (int c = 0; c < CF; ++c) {
    float v = pf[(size_t)c * HH * WW];
    vals[x * 97 + CE + c] = v;
    s += v; s2 += v * v;
  }
  mu = s * (1.f / CF);
  var = s2 * (1.f / CF) - mu * mu;
  mu_f[x] = mu; rs_f[x] = rsqrtf(var + 1e-5f);
  __syncthreads();
  float* orow = ox + ((size_t)(b * HH + y)) * WW * CIN;
  for (int i = 0; i < CIN; ++i) {       // 128*96 elements, coalesced writes
    int e = i * WW + t;
    int xx = e / CIN, c = e % CIN;
    float v = vals[xx * 97 + c];
    float o = (c < CE) ? (v - mu_e[xx]) * rs_e[xx]
                       : (v - mu_f[xx]) * rs_f[xx];
    orow[e] = o * lnw[c] + lnb[c];
  }
}

// 3x3 conv 96->27 (offset raw, mask = 2*sigmoid). One pixel per thread,
// weights are wave-uniform -> scalar loads.
__global__ __launch_bounds__(256) void conv_offmask(
    const float* __restrict__ ox, const float* __restrict__ wcomb,
    const float* __restrict__ off_b, const float* __restrict__ mod_b,
    float* __restrict__ offmask) {
  int p = blockIdx.x * 256 + threadIdx.x;
  int b = p / (HH * WW);
  int rem = p % (HH * WW);
  int y = rem / WW, x = rem % WW;
  float acc[COM];
#pragma unroll
  for (int oc = 0; oc < 18; ++oc) acc[oc] = off_b[oc];
#pragma unroll
  for (int oc = 0; oc < 9; ++oc) acc[18 + oc] = mod_b[oc];
  for (int ky = 0; ky < 3; ++ky) {
    int yy = y + ky - 1;
    if (yy < 0 || yy >= HH) continue;
    for (int kx = 0; kx < 3; ++kx) {
      int xx = x + kx - 1;
      if (xx < 0 || xx >= WW) continue;
      const float* src = ox + ((size_t)((b * HH + yy) * WW + xx)) * CIN;
      const float* wp = wcomb + (ky * 3 + kx) * CIN * COM;
      for (int c = 0; c < CIN; ++c) {
        float v = src[c];
#pragma unroll
        for (int oc = 0; oc < COM; ++oc)
          acc[oc] += v * wp[c * COM + oc];
      }
    }
  }
  float* o = offmask + (size_t)p * COM;
#pragma unroll
  for (int oc = 0; oc < 18; ++oc) o[oc] = acc[oc];
#pragma unroll
  for (int oc = 0; oc < 9; ++oc) {
    float z = acc[18 + oc];
    o[18 + oc] = 2.f / (1.f + __expf(-z));
  }
}

// Deformable conv + bias + leaky-relu + channel-LN, fused.
// 64 pixels/block (one row segment), 256 threads.
// Per tap k: stage wk slice + bilinear-sampled tile into LDS, then a
// register-blocked (4 oc x 4 px per thread) FMA matmul.
__global__ __launch_bounds__(256) void deform_ln(
    const float* __restrict__ ox, const float* __restrict__ offmask,
    const float* __restrict__ wkt, const float* __restrict__ reg_b,
    const float* __restrict__ ln_w, const float* __restrict__ ln_b,
    float* __restrict__ out) {
  __shared__ float wk_lds[CIN * COUT / KK * KK / KK];  // placeholder avoided below
  // (real buffers)
  __shared__ float samp[TPB * CIN];          // 6144 floats = 24 KB (reused as out-transpose)
  __shared__ float offm[TPB * COM];          // 1728 floats
  __shared__ float wk[CIN * COUT];           // 6144 floats = 24 KB

  int t = threadIdx.x;
  int p0 = blockIdx.x * TPB;
  int b = p0 / (HH * WW);
  int rem = p0 % (HH * WW);
  int y = rem / WW;
  int x0 = rem % WW;

  for (int e = t; e < TPB * COM; e += 256)
    offm[e] = offmask[(size_t)p0 * COM + e];

  float acc[4][4];
#pragma unroll
  for (int j = 0; j < 4; ++j)
#pragma unroll
    for (int q = 0; q < 4; ++q) acc[j][q] = 0.f;

  int ocb = (t & 15) * 4;   // 4 consecutive out-channels
  int tpg = t >> 4;         // pixel group: pixels tpg*4 .. tpg*4+3
  __syncthreads();

  for (int k = 0; k < KK; ++k) {
    // stage weight slice wk[c][oc] for this tap (coalesced float4)
    const float4* wsrc = (const float4*)(wkt + k * CIN * COUT);
    float4* wdst = (float4*)wk;
    for (int e = t; e < CIN * COUT / 4; e += 256) wdst[e] = wsrc[e];

    // bilinear sampling: 64 px * 96 ch values
    int kdy = k / 3 - 1, kdx = k % 3 - 1;
    for (int i = 0; i < TPB * CIN / 256; ++i) {   // 24 iters
      int e = i * 256 + t;
      int tp = e / CIN, c = e % CIN;
      float dy = offm[tp * COM + 2 * k];
      float dx = offm[tp * COM + 2 * k + 1];
      float m  = offm[tp * COM + 18 + k];
      float psy = (float)(y + kdy) + dy;
      float psx = (float)(x0 + tp + kdx) + dx;
      float fy0 = floorf(psy), fx0 = floorf(psx);
      float wy1 = psy - fy0, wx1 = psx - fx0;
      float wy0 = 1.f - wy1, wx0 = 1.f - wx1;
      int iy0 = (int)fy0, ix0 = (int)fx0;
      int iy1 = iy0 + 1, ix1 = ix0 + 1;
      int cy0 = min(max(iy0, 0), HH - 1), cy1 = min(max(iy1, 0), HH - 1);
      int cx0 = min(max(ix0, 0), WW - 1), cx1 = min(max(ix1, 0), WW - 1);
      float vy0 = (iy0 >= 0 && iy0 < HH) ? 1.f : 0.f;
      float vy1 = (iy1 >= 0 && iy1 < HH) ? 1.f : 0.f;
      float vx0 = (ix0 >= 0 && ix0 < WW) ? 1.f : 0.f;
      float vx1 = (ix1 >= 0 && ix1 < WW) ? 1.f : 0.f;
      const float* base = ox + (size_t)b * HH * WW * CIN + c;
      float v00 = base[(size_t)(cy0 * WW + cx0) * CIN];
      float v01 = base[(size_t)(cy0 * WW + cx1) * CIN];
      float v10 = base[(size_t)(cy1 * WW + cx0) * CIN];
      float v11 = base[(size_t)(cy1 * WW + cx1) * CIN];
      float sv = v00 * (wy0 * wx0 * vy0 * vx0) + v01 * (wy0 * wx1 * vy0 * vx1)
               + v10 * (wy1 * wx0 * vy1 * vx0) + v11 * (wy1 * wx1 * vy1 * vx1);
      samp[e] = sv * m;
    }
    __syncthreads();

    // matmul: acc[j][q] += sum_c samp[tp][c] * wk[c][oc]
    for (int c4 = 0; c4 < CIN; c4 += 4) {
      float4 s0 = *(const float4*)&samp[(tpg * 4 + 0) * CIN + c4];
      float4 s1 = *(const float4*)&samp[(tpg * 4 + 1) * CIN + c4];
      float4 s2 = *(const float4*)&samp[(tpg * 4 + 2) * CIN + c4];
      float4 s3 = *(const float4*)&samp[(tpg * 4 + 3) * CIN + c4];
      float4 w0 = *(const float4*)&wk[(c4 + 0) * COUT + ocb];
      float4 w1 = *(const float4*)&wk[(c4 + 1) * COUT + ocb];
      float4 w2 = *(const float4*)&wk[(c4 + 2) * COUT + ocb];
      float4 w3 = *(const float4*)&wk[(c4 + 3) * COUT + ocb];
#define UPD(J, S) \
      acc[J][0] += S.x * w0.x + S.y * w1.x + S.z * w2.x + S.w * w3.x; \
      acc[J][1] += S.x * w0.y + S.y * w1.y + S.z * w2.y + S.w * w3.y; \
      acc[J][2] += S.x * w0.z + S.y * w1.z + S.z * w2.z + S.w * w3.z; \
      acc[J][3] += S.x * w0.w + S.y * w1.w + S.z * w2.w + S.w * w3.w;
      UPD(0, s0) UPD(1, s1) UPD(2, s2) UPD(3, s3)
#undef UPD
    }
    __syncthreads();
  }

  // bias + leaky relu + LN over 64 channels (per pixel)
  float4 bia = *(const float4*)&reg_b[ocb];
  float4 lw  = *(const float4*)&ln_w[ocb];
  float4 lb  = *(const float4*)&ln_b[ocb];
  const float bi[4] = {bia.x, bia.y, bia.z, bia.w};
  const float lwv[4] = {lw.x, lw.y, lw.z, lw.w};
  const float lbv[4] = {lb.x, lb.y, lb.z, lb.w};
  float* tmp = samp;   // reuse (last barrier of k-loop protects it)

#pragma unroll
  for (int j = 0; j < 4; ++j) {
    float vals4[4];
    float s = 0.f, s2 = 0.f;
#pragma unroll
    for (int q = 0; q < 4; ++q) {
      float v = acc[j][q] + bi[q];
      v = (v >= 0.f) ? v : 0.2f * v;
      vals4[q] = v;
      s += v; s2 += v * v;
    }
#pragma unroll
    for (int m = 1; m < 16; m <<= 1) {   // reduce over the 16-lane channel group
      s  += __shfl_xor(s, m);
      s2 += __shfl_xor(s2, m);
    }
    float mu = s * (1.f / COUT);
    float var = s2 * (1.f / COUT) - mu * mu;
    float rs = rsqrtf(var + 1e-5f);
    int tp = tpg * 4 + j;
#pragma unroll
    for (int q = 0; q < 4; ++q) {
      float o = (vals4[q] - mu) * rs * lwv[q] + lbv[q];
      tmp[(ocb + q) * 65 + tp] = o;      // padded stride 65
    }
  }
  __syncthreads();

  // coalesced NCHW store
  size_t obase = (size_t)b * COUT * HH * WW + (size_t)y * WW + x0;
  for (int i = 0; i < TPB * COUT / 256; ++i) {   // 16 iters
    int e = i * 256 + t;
    int oc = e / TPB, tp = e % TPB;
    out[obase + (size_t)oc * HH * WW + tp] = tmp[oc * 65 + tp];
  }
}

extern "C" void kernel_launch(void* const* d_in, const int* in_sizes, int n_in,
                              void* d_out, int out_size, void* d_ws, size_t ws_size,
                              hipStream_t stream) {
  const float* evt      = (const float*)d_in[0];
  const float* efn      = (const float*)d_in[1];
  const float* ln_evt_w = (const float*)d_in[2];
  const float* ln_evt_b = (const float*)d_in[3];
  const float* ln_ef_w  = (const float*)d_in[4];
  const float* ln_ef_b  = (const float*)d_in[5];
  const float* ln_al_w  = (const float*)d_in[6];
  const float* ln_al_b  = (const float*)d_in[7];
  const float* off_w    = (const float*)d_in[8];
  const float* off_b    = (const float*)d_in[9];
  const float* mod_w    = (const float*)d_in[10];
  const float* mod_b    = (const float*)d_in[11];
  const float* reg_w    = (const float*)d_in[12];
  const float* reg_b    = (const float*)d_in[13];
  float* ws  = (float*)d_ws;
  float* out = (float*)d_out;

  prep_weights<<<64, 256, 0, stream>>>(off_w, mod_w, reg_w, ws);
  ln_concat<<<BATCH * HH, 128, 0, stream>>>(
      evt, efn, ln_evt_w, ln_evt_b, ln_ef_w, ln_ef_b, ws + OX_OFF);
  conv_offmask<<<BATCH * HH * WW / 256, 256, 0, stream>>>(
      ws + OX_OFF, ws + WC_OFF, off_b, mod_b, ws + OM_OFF);
  deform_ln<<<BATCH * HH * WW / TPB, 256, 0, stream>>>(
      ws + OX_OFF, ws + OM_OFF, ws + WK_OFF, reg_b, ln_al_w, ln_al_b, out);
}

// Round 3
// 181.072 us; speedup vs baseline: 2.9716x; 2.9716x over previous
//
#include <hip/hip_runtime.h>
#include <hip/hip_bf16.h>

#define BATCH 4
#define HH 128
#define WW 128
#define CE 32
#define CF 64
#define CIN 96
#define KK 9
#define COUT 64

typedef __bf16 bf16x8 __attribute__((ext_vector_type(8)));
typedef float f32x4 __attribute__((ext_vector_type(4)));

#define MFMA16(a, b, c) __builtin_amdgcn_mfma_f32_16x16x32_bf16(a, b, c, 0, 0, 0)

// ---- workspace byte offsets ----
#define OX_BYTES   (BATCH * HH * WW * CIN * 2)      // 12,582,912  bf16 NHWC
#define OFFM_OFFB  OX_BYTES
#define OFFM_BYTES (BATCH * HH * WW * 27 * 4)       // 7,077,888   f32 [p][27]
#define WCT_OFFB   (OFFM_OFFB + OFFM_BYTES)
#define WCT_BYTES  (32 * 864 * 2)                   // 55,296      bf16 [32][864]
#define WKT_OFFB   (WCT_OFFB + WCT_BYTES)
#define WKT_BYTES  (64 * 864 * 2)                   // 110,592     bf16 [64][864]

// Repack weights to bf16, K-major (k = tap*96 + c), N-transposed:
//   wcombT[oc32][864]  (oc<18 offset conv, 18..26 mask conv, 27..31 zero)
//   wkT[oc64][864]
__global__ void prep_weights(const float* __restrict__ off_w,
                             const float* __restrict__ mod_w,
                             const float* __restrict__ reg_w,
                             __hip_bfloat16* __restrict__ wcombT,
                             __hip_bfloat16* __restrict__ wkT) {
  int e = blockIdx.x * 256 + threadIdx.x;
  const int TOT1 = 32 * 864;
  const int TOT2 = 64 * 864;
  if (e < TOT1) {
    int oc = e / 864, k = e % 864;
    int tap = k / 96, c = k % 96;
    float v = 0.f;
    if (oc < 18)      v = off_w[(oc * CIN + c) * KK + tap];
    else if (oc < 27) v = mod_w[((oc - 18) * CIN + c) * KK + tap];
    wcombT[e] = __float2bfloat16(v);
  } else if (e < TOT1 + TOT2) {
    int e2 = e - TOT1;
    int oc = e2 / 864, k = e2 % 864;
    int tap = k / 96, c = k % 96;
    wkT[e2] = __float2bfloat16(reg_w[(oc * CIN + c) * KK + tap]);
  }
}

// Fused LN(evt)+LN(efnet)+concat -> ox bf16 NHWC [B][H][W][96]
__global__ __launch_bounds__(128) void ln_concat(
    const float* __restrict__ evt, const float* __restrict__ efn,
    const float* __restrict__ w_e, const float* __restrict__ b_e,
    const float* __restrict__ w_f, const float* __restrict__ b_f,
    __hip_bfloat16* __restrict__ ox) {
  __shared__ float vals[WW * 97];
  __shared__ float mu_e[WW], rs_e[WW], mu_f[WW], rs_f[WW];
  __shared__ float lnw[CIN], lnb[CIN];
  int t = threadIdx.x;
  int b = blockIdx.x >> 7, y = blockIdx.x & 127;
  if (t < CIN) {
    lnw[t] = (t < CE) ? w_e[t] : w_f[t - CE];
    lnb[t] = (t < CE) ? b_e[t] : b_f[t - CE];
  }
  int x = t;
  float s = 0.f, s2 = 0.f;
  const float* pe = evt + ((size_t)(b * CE) * HH + y) * WW + x;
  for (int c = 0; c < CE; ++c) {
    float v = pe[(size_t)c * HH * WW];
    vals[x * 97 + c] = v;
    s += v; s2 += v * v;
  }
  float mu = s * (1.f / CE);
  float var = s2 * (1.f / CE) - mu * mu;
  mu_e[x] = mu; rs_e[x] = rsqrtf(var + 1e-5f);
  s = 0.f; s2 = 0.f;
  const float* pf = efn + ((size_t)(b * CF) * HH + y) * WW + x;
  for (int c = 0; c < CF; ++c) {
    float v = pf[(size_t)c * HH * WW];
    vals[x * 97 + CE + c] = v;
    s += v; s2 += v * v;
  }
  mu = s * (1.f / CF);
  var = s2 * (1.f / CF) - mu * mu;
  mu_f[x] = mu; rs_f[x] = rsqrtf(var + 1e-5f);
  __syncthreads();
  uint* orow = (uint*)(ox + (size_t)blockIdx.x * WW * CIN);
  for (int i = 0; i < 48; ++i) {                 // 6144 uints, coalesced
    int g = i * 128 + t;
    int xx = g / 48, c = (g % 48) * 2;
    float v0 = vals[xx * 97 + c], v1 = vals[xx * 97 + c + 1];
    float o0 = (c < CE) ? (v0 - mu_e[xx]) * rs_e[xx] : (v0 - mu_f[xx]) * rs_f[xx];
    float o1 = (c + 1 < CE) ? (v1 - mu_e[xx]) * rs_e[xx] : (v1 - mu_f[xx]) * rs_f[xx];
    o0 = o0 * lnw[c] + lnb[c];
    o1 = o1 * lnw[c + 1] + lnb[c + 1];
    __hip_bfloat16 h0 = __float2bfloat16(o0), h1 = __float2bfloat16(o1);
    orow[g] = ((uint)*(unsigned short*)&h1 << 16) | (uint)*(unsigned short*)&h0;
  }
}

// 3x3 conv 96->27 via MFMA. Block: 64-px row segment, 256 thr (4 waves).
// A tile: [3 rows][66 px][104 pad] bf16 in LDS. B: per-tap [32][104].
__global__ __launch_bounds__(256) void conv_offmask_mfma(
    const __hip_bfloat16* __restrict__ ox,
    const __hip_bfloat16* __restrict__ wcombT,
    const float* __restrict__ off_b, const float* __restrict__ mod_b,
    float* __restrict__ offm) {
  __shared__ char smem[47872];
  short* At = (short*)smem;              // 3*66*104 shorts = 41184 B
  short* Bt = (short*)(smem + 41184);    // 32*104 shorts = 6656 B
  float* outl = (float*)smem;            // [64][28] f32 alias (epilogue)

  int t = threadIdx.x;
  int p0 = blockIdx.x * 64;
  int b = p0 >> 14;
  int y = (p0 >> 7) & 127;
  int x0 = p0 & 127;

  for (int u = t; u < 3 * 66 * 12; u += 256) {
    int c8 = u % 12;
    int pw = u / 12;
    int w = pw % 66;
    int r = pw / 66;
    int yy = y + r - 1;
    int xx = x0 + w - 1;
    uint4 v = {0u, 0u, 0u, 0u};
    if ((unsigned)yy < 128u && (unsigned)xx < 128u)
      v = *(const uint4*)(ox + (size_t)((b << 14) + (yy << 7) + xx) * CIN + c8 * 8);
    *(uint4*)&At[(r * 66 + w) * 104 + c8 * 8] = v;
  }

  int lane = t & 63;
  int wv = t >> 6;
  int mw = wv >> 1, nw = wv & 1;
  int lr = lane & 15, lg = lane >> 4;

  f32x4 acc0 = {0.f, 0.f, 0.f, 0.f}, acc1 = {0.f, 0.f, 0.f, 0.f};

  for (int tap = 0; tap < 9; ++tap) {
    for (int u = t; u < 384; u += 256) {
      int c8 = u % 12, oc = u / 12;
      *(uint4*)&Bt[oc * 104 + c8 * 8] =
          *(const uint4*)(wcombT + oc * 864 + tap * 96 + c8 * 8);
    }
    __syncthreads();
    int dy = tap / 3, dx = tap % 3;
#pragma unroll
    for (int ks = 0; ks < 3; ++ks) {
      int ko = ks * 32 + lg * 8;
      bf16x8 bf = *(const bf16x8*)&Bt[(nw * 16 + lr) * 104 + ko];
      bf16x8 a0 = *(const bf16x8*)&At[(dy * 66 + mw * 32 + lr + dx) * 104 + ko];
      bf16x8 a1 = *(const bf16x8*)&At[(dy * 66 + mw * 32 + 16 + lr + dx) * 104 + ko];
      acc0 = MFMA16(a0, bf, acc0);
      acc1 = MFMA16(a1, bf, acc1);
    }
    __syncthreads();
  }

  int oc = nw * 16 + lr;
  float bia = 0.f;
  if (oc < 18) bia = off_b[oc];
  else if (oc < 27) bia = mod_b[oc - 18];
#pragma unroll
  for (int mi = 0; mi < 2; ++mi) {
    f32x4 a = mi ? acc1 : acc0;
#pragma unroll
    for (int r = 0; r < 4; ++r) {
      int px = mw * 32 + mi * 16 + lg * 4 + r;
      if (oc < 27) {
        float v = a[r] + bia;
        if (oc >= 18) v = 2.f / (1.f + __expf(-v));
        outl[px * 28 + oc] = v;
      }
    }
  }
  __syncthreads();
  for (int e = t; e < 64 * 27; e += 256) {
    int px = e / 27, c = e % 27;
    offm[(size_t)p0 * 27 + e] = outl[px * 28 + c];
  }
}

// Deformable conv (MFMA) + bias + leaky + channel-LN, fused.
// Block: 64-px segment, 256 thr. Per tap: bilinear params once per (px,tap),
// vectorized 8-ch bf16 gather/blend into LDS, 3x K-32 MFMA steps.
__global__ __launch_bounds__(256) void deform_ln_mfma(
    const __hip_bfloat16* __restrict__ ox,
    const float* __restrict__ offm,
    const __hip_bfloat16* __restrict__ wkT,
    const float* __restrict__ reg_b,
    const float* __restrict__ lnw, const float* __restrict__ lnb,
    float* __restrict__ out) {
  __shared__ char smem[28672];
  int*   sI = (int*)smem;               // [64][4] corner idx (premult *96)
  float* sW = (float*)(smem + 1024);    // [64][4] corner weights (mask folded)
  short* Sa = (short*)(smem + 2048);    // samp [64][104] bf16
  short* Wk = (short*)(smem + 15360);   // wk   [64][104] bf16
  float* outl = (float*)(smem + 2048);  // [64][68] f32 alias (epilogue)

  int t = threadIdx.x;
  int p0 = blockIdx.x * 64;
  int b = p0 >> 14;
  int y = (p0 >> 7) & 127;
  int x0 = p0 & 127;
  const __hip_bfloat16* oxb = ox + ((size_t)b << 14) * CIN;

  int lane = t & 63, wv = t >> 6;
  int mw = wv >> 1, nw = wv & 1;
  int lr = lane & 15, lg = lane >> 4;

  f32x4 a00 = {0.f,0.f,0.f,0.f}, a01 = {0.f,0.f,0.f,0.f};
  f32x4 a10 = {0.f,0.f,0.f,0.f}, a11 = {0.f,0.f,0.f,0.f};

  for (int tap = 0; tap < 9; ++tap) {
    for (int u = t; u < 768; u += 256) {          // stage per-tap weights
      int c8 = u % 12, oc = u / 12;
      *(uint4*)&Wk[oc * 104 + c8 * 8] =
          *(const uint4*)(wkT + oc * 864 + tap * 96 + c8 * 8);
    }
    if (t < 64) {                                  // bilinear params, once per px
      int px = t;
      const float* om = offm + (size_t)(p0 + px) * 27;
      float dyv = om[2 * tap], dxv = om[2 * tap + 1], mk = om[18 + tap];
      float psy = (float)(y + tap / 3 - 1) + dyv;
      float psx = (float)(x0 + px + tap % 3 - 1) + dxv;
      float fy = floorf(psy), fx = floorf(psx);
      float wy1 = psy - fy, wx1 = psx - fx;
      float wy0 = 1.f - wy1, wx0 = 1.f - wx1;
      int iy0 = (int)fy, ix0 = (int)fx;
      int iy1 = iy0 + 1, ix1 = ix0 + 1;
      float vy0 = ((unsigned)iy0 < 128u) ? 1.f : 0.f;
      float vy1 = ((unsigned)iy1 < 128u) ? 1.f : 0.f;
      float vx0 = ((unsigned)ix0 < 128u) ? 1.f : 0.f;
      float vx1 = ((unsigned)ix1 < 128u) ? 1.f : 0.f;
      int cy0 = min(max(iy0, 0), 127), cy1 = min(max(iy1, 0), 127);
      int cx0 = min(max(ix0, 0), 127), cx1 = min(max(ix1, 0), 127);
      sI[px * 4 + 0] = ((cy0 << 7) + cx0) * CIN;
      sI[px * 4 + 1] = ((cy0 << 7) + cx1) * CIN;
      sI[px * 4 + 2] = ((cy1 << 7) + cx0) * CIN;
      sI[px * 4 + 3] = ((cy1 << 7) + cx1) * CIN;
      sW[px * 4 + 0] = wy0 * wx0 * vy0 * vx0 * mk;
      sW[px * 4 + 1] = wy0 * wx1 * vy0 * vx1 * mk;
      sW[px * 4 + 2] = wy1 * wx0 * vy1 * vx0 * mk;
      sW[px * 4 + 3] = wy1 * wx1 * vy1 * vx1 * mk;
    }
    __syncthreads();
#pragma unroll
    for (int it = 0; it < 3; ++it) {               // sample: 768 8-ch units
      int u = it * 256 + t;
      int px = u / 12, c8 = u % 12;
      const int* si = sI + px * 4;
      const float* sw = sW + px * 4;
      uint4 q0 = *(const uint4*)(oxb + si[0] + c8 * 8);
      uint4 q1 = *(const uint4*)(oxb + si[1] + c8 * 8);
      uint4 q2 = *(const uint4*)(oxb + si[2] + c8 * 8);
      uint4 q3 = *(const uint4*)(oxb + si[3] + c8 * 8);
      float w0 = sw[0], w1 = sw[1], w2 = sw[2], w3 = sw[3];
      uint rr[4];
#pragma unroll
      for (int j = 0; j < 4; ++j) {
        uint u0 = ((uint*)&q0)[j], u1 = ((uint*)&q1)[j];
        uint u2 = ((uint*)&q2)[j], u3 = ((uint*)&q3)[j];
        float lo = w0 * __uint_as_float(u0 << 16) + w1 * __uint_as_float(u1 << 16)
                 + w2 * __uint_as_float(u2 << 16) + w3 * __uint_as_float(u3 << 16);
        float hi = w0 * __uint_as_float(u0 & 0xffff0000u) + w1 * __uint_as_float(u1 & 0xffff0000u)
                 + w2 * __uint_as_float(u2 & 0xffff0000u) + w3 * __uint_as_float(u3 & 0xffff0000u);
        __hip_bfloat16 bl = __float2bfloat16(lo);
        __hip_bfloat16 bh = __float2bfloat16(hi);
        rr[j] = ((uint)*(unsigned short*)&bh << 16) | (uint)*(unsigned short*)&bl;
      }
      uint4 rv = {rr[0], rr[1], rr[2], rr[3]};
      *(uint4*)&Sa[px * 104 + c8 * 8] = rv;
    }
    __syncthreads();
#pragma unroll
    for (int ks = 0; ks < 3; ++ks) {               // MFMA: 4 tiles per wave
      int ko = ks * 32 + lg * 8;
      bf16x8 fa0 = *(const bf16x8*)&Sa[(mw * 32 + lr) * 104 + ko];
      bf16x8 fa1 = *(const bf16x8*)&Sa[(mw * 32 + 16 + lr) * 104 + ko];
      bf16x8 fb0 = *(const bf16x8*)&Wk[(nw * 32 + lr) * 104 + ko];
      bf16x8 fb1 = *(const bf16x8*)&Wk[(nw * 32 + 16 + lr) * 104 + ko];
      a00 = MFMA16(fa0, fb0, a00);
      a01 = MFMA16(fa0, fb1, a01);
      a10 = MFMA16(fa1, fb0, a10);
      a11 = MFMA16(fa1, fb1, a11);
    }
    __syncthreads();
  }

  // bias + leaky into outl[px][oc] (stride 68)
#pragma unroll
  for (int mi = 0; mi < 2; ++mi)
#pragma unroll
  for (int ni = 0; ni < 2; ++ni) {
    int oc = nw * 32 + ni * 16 + lr;
    float bia = reg_b[oc];
    f32x4 a = (mi == 0) ? (ni == 0 ? a00 : a01) : (ni == 0 ? a10 : a11);
#pragma unroll
    for (int r = 0; r < 4; ++r) {
      int px = mw * 32 + mi * 16 + lg * 4 + r;
      float v = a[r] + bia;
      v = (v >= 0.f) ? v : 0.2f * v;
      outl[px * 68 + oc] = v;
    }
  }
  __syncthreads();

  // channel-LN (64 ch) per px: 4 lanes per px, 16 ch each
  {
    int px = t >> 2, part = t & 3;
    float s = 0.f, s2 = 0.f;
#pragma unroll
    for (int j = 0; j < 16; ++j) {
      float v = outl[px * 68 + part * 16 + j];
      s += v; s2 += v * v;
    }
    s += __shfl_xor(s, 1); s2 += __shfl_xor(s2, 1);
    s += __shfl_xor(s, 2); s2 += __shfl_xor(s2, 2);
    float mu = s * (1.f / 64.f);
    float var = s2 * (1.f / 64.f) - mu * mu;
    float rs = rsqrtf(var + 1e-5f);
    size_t ob = (size_t)b * COUT * 16384 + (size_t)y * 128 + x0 + px;
#pragma unroll
    for (int j = 0; j < 16; ++j) {
      int oc = part * 16 + j;
      float v = outl[px * 68 + oc];
      out[ob + (size_t)oc * 16384] = (v - mu) * rs * lnw[oc] + lnb[oc];
    }
  }
}

extern "C" void kernel_launch(void* const* d_in, const int* in_sizes, int n_in,
                              void* d_out, int out_size, void* d_ws, size_t ws_size,
                              hipStream_t stream) {
  const float* evt      = (const float*)d_in[0];
  const float* efn      = (const float*)d_in[1];
  const float* ln_evt_w = (const float*)d_in[2];
  const float* ln_evt_b = (const float*)d_in[3];
  const float* ln_ef_w  = (const float*)d_in[4];
  const float* ln_ef_b  = (const float*)d_in[5];
  const float* ln_al_w  = (const float*)d_in[6];
  const float* ln_al_b  = (const float*)d_in[7];
  const float* off_w    = (const float*)d_in[8];
  const float* off_b    = (const float*)d_in[9];
  const float* mod_w    = (const float*)d_in[10];
  const float* mod_b    = (const float*)d_in[11];
  const float* reg_w    = (const float*)d_in[12];
  const float* reg_b    = (const float*)d_in[13];
  float* out = (float*)d_out;

  char* wsb = (char*)d_ws;
  __hip_bfloat16* oxb    = (__hip_bfloat16*)wsb;
  float*          offm   = (float*)(wsb + OFFM_OFFB);
  __hip_bfloat16* wcombT = (__hip_bfloat16*)(wsb + WCT_OFFB);
  __hip_bfloat16* wkT    = (__hip_bfloat16*)(wsb + WKT_OFFB);

  prep_weights<<<(32 * 864 + 64 * 864 + 255) / 256, 256, 0, stream>>>(
      off_w, mod_w, reg_w, wcombT, wkT);
  ln_concat<<<BATCH * HH, 128, 0, stream>>>(
      evt, efn, ln_evt_w, ln_evt_b, ln_ef_w, ln_ef_b, oxb);
  conv_offmask_mfma<<<BATCH * HH * WW / 64, 256, 0, stream>>>(
      oxb, wcombT, off_b, mod_b, offm);
  deform_ln_mfma<<<BATCH * HH * WW / 64, 256, 0, stream>>>(
      oxb, offm, wkT, reg_b, ln_al_w, ln_al_b, out);
}

// Round 4
// 176.011 us; speedup vs baseline: 3.0570x; 1.0288x over previous
//
#include <hip/hip_runtime.h>
#include <hip/hip_bf16.h>

#define BATCH 4
#define HH 128
#define WW 128
#define CE 32
#define CF 64
#define CIN 96
#define KK 9
#define COUT 64

typedef __bf16 bf16x8 __attribute__((ext_vector_type(8)));
typedef float f32x4 __attribute__((ext_vector_type(4)));

#define MFMA16(a, b, c) __builtin_amdgcn_mfma_f32_16x16x32_bf16(a, b, c, 0, 0, 0)

typedef union { uint4 u; bf16x8 v; } U8;

// ---- workspace byte offsets ----
#define OX_BYTES   (BATCH * HH * WW * CIN * 2)      // 12,582,912  bf16 NHWC
#define OFFM_OFFB  OX_BYTES
#define OFFM_BYTES (BATCH * HH * WW * 27 * 4)       // 7,077,888   f32 [p][27]
#define WCT_OFFB   (OFFM_OFFB + OFFM_BYTES)
#define WCT_BYTES  (32 * 864 * 2)                   // 55,296      bf16 [32][864]
#define WKT_OFFB   (WCT_OFFB + WCT_BYTES)
#define WKT_BYTES  (64 * 864 * 2)                   // 110,592     bf16 [64][864]

// Repack weights to bf16, K-major (k = tap*96 + c), N-transposed:
//   wcombT[oc32][864]  (oc<18 offset conv, 18..26 mask conv, 27..31 zero)
//   wkT[oc64][864]
__global__ void prep_weights(const float* __restrict__ off_w,
                             const float* __restrict__ mod_w,
                             const float* __restrict__ reg_w,
                             __hip_bfloat16* __restrict__ wcombT,
                             __hip_bfloat16* __restrict__ wkT) {
  int e = blockIdx.x * 256 + threadIdx.x;
  const int TOT1 = 32 * 864;
  const int TOT2 = 64 * 864;
  if (e < TOT1) {
    int oc = e / 864, k = e % 864;
    int tap = k / 96, c = k % 96;
    float v = 0.f;
    if (oc < 18)      v = off_w[(oc * CIN + c) * KK + tap];
    else if (oc < 27) v = mod_w[((oc - 18) * CIN + c) * KK + tap];
    wcombT[e] = __float2bfloat16(v);
  } else if (e < TOT1 + TOT2) {
    int e2 = e - TOT1;
    int oc = e2 / 864, k = e2 % 864;
    int tap = k / 96, c = k % 96;
    wkT[e2] = __float2bfloat16(reg_w[(oc * CIN + c) * KK + tap]);
  }
}

// Fused LN(evt)+LN(efnet)+concat -> ox bf16 NHWC [B][H][W][96]
__global__ __launch_bounds__(128) void ln_concat(
    const float* __restrict__ evt, const float* __restrict__ efn,
    const float* __restrict__ w_e, const float* __restrict__ b_e,
    const float* __restrict__ w_f, const float* __restrict__ b_f,
    __hip_bfloat16* __restrict__ ox) {
  __shared__ float vals[WW * 97];
  __shared__ float mu_e[WW], rs_e[WW], mu_f[WW], rs_f[WW];
  __shared__ float lnw[CIN], lnb[CIN];
  int t = threadIdx.x;
  int b = blockIdx.x >> 7, y = blockIdx.x & 127;
  if (t < CIN) {
    lnw[t] = (t < CE) ? w_e[t] : w_f[t - CE];
    lnb[t] = (t < CE) ? b_e[t] : b_f[t - CE];
  }
  int x = t;
  float s = 0.f, s2 = 0.f;
  const float* pe = evt + ((size_t)(b * CE) * HH + y) * WW + x;
  for (int c = 0; c < CE; ++c) {
    float v = pe[(size_t)c * HH * WW];
    vals[x * 97 + c] = v;
    s += v; s2 += v * v;
  }
  float mu = s * (1.f / CE);
  float var = s2 * (1.f / CE) - mu * mu;
  mu_e[x] = mu; rs_e[x] = rsqrtf(var + 1e-5f);
  s = 0.f; s2 = 0.f;
  const float* pf = efn + ((size_t)(b * CF) * HH + y) * WW + x;
  for (int c = 0; c < CF; ++c) {
    float v = pf[(size_t)c * HH * WW];
    vals[x * 97 + CE + c] = v;
    s += v; s2 += v * v;
  }
  mu = s * (1.f / CF);
  var = s2 * (1.f / CF) - mu * mu;
  mu_f[x] = mu; rs_f[x] = rsqrtf(var + 1e-5f);
  __syncthreads();
  uint* orow = (uint*)(ox + (size_t)blockIdx.x * WW * CIN);
  for (int i = 0; i < 48; ++i) {                 // 6144 uints, coalesced
    int g = i * 128 + t;
    int xx = g / 48, c = (g % 48) * 2;
    float v0 = vals[xx * 97 + c], v1 = vals[xx * 97 + c + 1];
    float o0 = (c < CE) ? (v0 - mu_e[xx]) * rs_e[xx] : (v0 - mu_f[xx]) * rs_f[xx];
    float o1 = (c + 1 < CE) ? (v1 - mu_e[xx]) * rs_e[xx] : (v1 - mu_f[xx]) * rs_f[xx];
    o0 = o0 * lnw[c] + lnb[c];
    o1 = o1 * lnw[c + 1] + lnb[c + 1];
    __hip_bfloat16 h0 = __float2bfloat16(o0), h1 = __float2bfloat16(o1);
    orow[g] = ((uint)*(unsigned short*)&h1 << 16) | (uint)*(unsigned short*)&h0;
  }
}

// 3x3 conv 96->27 via MFMA, no-LDS matmul: A and B fragments loaded
// directly from global (each fragment run = one 64B cache line; L1/L2-hit
// thanks to XCD-chunked swizzle). Zero inner barriers.
__global__ __launch_bounds__(256) void conv_offmask_mfma(
    const __hip_bfloat16* __restrict__ ox,
    const __hip_bfloat16* __restrict__ wcombT,
    const float* __restrict__ off_b, const float* __restrict__ mod_b,
    float* __restrict__ offm) {
  __shared__ float outl[64 * 28];        // 7168 B epilogue transpose

  int bid = blockIdx.x;
  int wg = (bid & 7) * 128 + (bid >> 3); // XCD-chunked swizzle (1024 = 8*128)
  int p0 = wg * 64;
  int b = p0 >> 14;
  int y = (p0 >> 7) & 127;
  int x0 = p0 & 127;

  int t = threadIdx.x, lane = t & 63, wv = t >> 6;
  int mw = wv >> 1, nw = wv & 1;
  int lr = lane & 15, lg = lane >> 4;

  const __hip_bfloat16* oxb = ox + (((size_t)b) << 14) * CIN;
  const __hip_bfloat16* brow = wcombT + (size_t)(nw * 16 + lr) * 864;

  f32x4 acc0 = {0.f, 0.f, 0.f, 0.f}, acc1 = {0.f, 0.f, 0.f, 0.f};

#pragma unroll
  for (int tap = 0; tap < 9; ++tap) {
    int dy = tap / 3 - 1, dx = tap % 3 - 1;
    int yy = y + dy;
    int xx0 = x0 + mw * 32 + lr + dx;
    int xx1 = xx0 + 16;
    bool v0 = ((unsigned)yy < 128u) && ((unsigned)xx0 < 128u);
    bool v1 = ((unsigned)yy < 128u) && ((unsigned)xx1 < 128u);
    int cy = min(max(yy, 0), 127);
    int cx0 = min(max(xx0, 0), 127);
    int cx1 = min(max(xx1, 0), 127);
    const __hip_bfloat16* arow = oxb + ((size_t)(cy << 7)) * CIN;
#pragma unroll
    for (int ks = 0; ks < 3; ++ks) {
      int ko = ks * 32 + lg * 8;
      U8 a0, a1, bf;
      a0.u = *(const uint4*)(arow + cx0 * CIN + ko);
      a1.u = *(const uint4*)(arow + cx1 * CIN + ko);
      if (!v0) { a0.u.x = 0; a0.u.y = 0; a0.u.z = 0; a0.u.w = 0; }
      if (!v1) { a1.u.x = 0; a1.u.y = 0; a1.u.z = 0; a1.u.w = 0; }
      bf.u = *(const uint4*)(brow + tap * 96 + ko);
      acc0 = MFMA16(a0.v, bf.v, acc0);
      acc1 = MFMA16(a1.v, bf.v, acc1);
    }
  }

  int oc = nw * 16 + lr;
  float bia = 0.f;
  if (oc < 18) bia = off_b[oc];
  else if (oc < 27) bia = mod_b[oc - 18];
#pragma unroll
  for (int mi = 0; mi < 2; ++mi) {
    f32x4 a = mi ? acc1 : acc0;
#pragma unroll
    for (int r = 0; r < 4; ++r) {
      int px = mw * 32 + mi * 16 + lg * 4 + r;
      if (oc < 27) {
        float v = a[r] + bia;
        if (oc >= 18) v = 2.f / (1.f + __expf(-v));
        outl[px * 28 + oc] = v;
      }
    }
  }
  __syncthreads();
  for (int e = t; e < 64 * 27; e += 256) {
    int px = e / 27, c = e % 27;
    offm[(size_t)p0 * 27 + e] = outl[px * 28 + c];
  }
}

// Deformable conv (MFMA) + bias + leaky + channel-LN, fused.
// XCD-chunked swizzle; all-tap bilinear params precomputed; Wk fragments
// direct from global; Sa double-buffered -> 1 barrier per tap.
__global__ __launch_bounds__(256) void deform_ln_mfma(
    const __hip_bfloat16* __restrict__ ox,
    const float* __restrict__ offm,
    const __hip_bfloat16* __restrict__ wkT,
    const float* __restrict__ reg_b,
    const float* __restrict__ lnw, const float* __restrict__ lnb,
    float* __restrict__ out) {
  __shared__ char smem[45056];
  int*   sI  = (int*)smem;                 // [9*64][4] corner idx (*96)   9216 B
  float* sW  = (float*)(smem + 9216);      // [9*64][4] corner weights     9216 B
  short* SaA = (short*)(smem + 18432);     // samp buf A [64][104]        13312 B
  short* SaB = (short*)(smem + 31744);     // samp buf B [64][104]        13312 B
  float* outl = (float*)smem;              // [64][68] f32 alias (epilogue)

  int bid = blockIdx.x;
  int wg = (bid & 7) * 128 + (bid >> 3);   // XCD-chunked swizzle
  int p0 = wg * 64;
  int b = p0 >> 14;
  int y = (p0 >> 7) & 127;
  int x0 = p0 & 127;
  const __hip_bfloat16* oxb = ox + (((size_t)b) << 14) * CIN;

  int t = threadIdx.x, lane = t & 63, wv = t >> 6;
  int mw = wv >> 1, nw = wv & 1;
  int lr = lane & 15, lg = lane >> 4;

  // precompute bilinear params for all 9 taps x 64 px
  for (int u = t; u < 576; u += 256) {
    int px = u & 63, tap = u >> 6;
    const float* om = offm + (size_t)(p0 + px) * 27;
    float dyv = om[2 * tap], dxv = om[2 * tap + 1], mk = om[18 + tap];
    float psy = (float)(y + tap / 3 - 1) + dyv;
    float psx = (float)(x0 + px + tap % 3 - 1) + dxv;
    float fy = floorf(psy), fx = floorf(psx);
    float wy1 = psy - fy, wx1 = psx - fx;
    float wy0 = 1.f - wy1, wx0 = 1.f - wx1;
    int iy0 = (int)fy, ix0 = (int)fx;
    int iy1 = iy0 + 1, ix1 = ix0 + 1;
    float vy0 = ((unsigned)iy0 < 128u) ? 1.f : 0.f;
    float vy1 = ((unsigned)iy1 < 128u) ? 1.f : 0.f;
    float vx0 = ((unsigned)ix0 < 128u) ? 1.f : 0.f;
    float vx1 = ((unsigned)ix1 < 128u) ? 1.f : 0.f;
    int cy0 = min(max(iy0, 0), 127), cy1 = min(max(iy1, 0), 127);
    int cx0 = min(max(ix0, 0), 127), cx1 = min(max(ix1, 0), 127);
    int base = u * 4;
    sI[base + 0] = ((cy0 << 7) + cx0) * CIN;
    sI[base + 1] = ((cy0 << 7) + cx1) * CIN;
    sI[base + 2] = ((cy1 << 7) + cx0) * CIN;
    sI[base + 3] = ((cy1 << 7) + cx1) * CIN;
    sW[base + 0] = wy0 * wx0 * vy0 * vx0 * mk;
    sW[base + 1] = wy0 * wx1 * vy0 * vx1 * mk;
    sW[base + 2] = wy1 * wx0 * vy1 * vx0 * mk;
    sW[base + 3] = wy1 * wx1 * vy1 * vx1 * mk;
  }
  __syncthreads();

  f32x4 a00 = {0.f,0.f,0.f,0.f}, a01 = {0.f,0.f,0.f,0.f};
  f32x4 a10 = {0.f,0.f,0.f,0.f}, a11 = {0.f,0.f,0.f,0.f};

  const __hip_bfloat16* wb0 = wkT + (size_t)(nw * 32 + lr) * 864;
  const __hip_bfloat16* wb1 = wkT + (size_t)(nw * 32 + 16 + lr) * 864;

  for (int tap = 0; tap < 9; ++tap) {
    short* S = (tap & 1) ? SaB : SaA;
    // sample: 768 8-ch units -> S
#pragma unroll
    for (int it = 0; it < 3; ++it) {
      int u = it * 256 + t;
      int px = u / 12, c8 = u % 12;
      int pb = (tap * 64 + px) * 4;
      const int* si = sI + pb;
      const float* sw = sW + pb;
      uint4 q0 = *(const uint4*)(oxb + si[0] + c8 * 8);
      uint4 q1 = *(const uint4*)(oxb + si[1] + c8 * 8);
      uint4 q2 = *(const uint4*)(oxb + si[2] + c8 * 8);
      uint4 q3 = *(const uint4*)(oxb + si[3] + c8 * 8);
      float w0 = sw[0], w1 = sw[1], w2 = sw[2], w3 = sw[3];
      uint rr[4];
#pragma unroll
      for (int j = 0; j < 4; ++j) {
        uint u0 = ((uint*)&q0)[j], u1 = ((uint*)&q1)[j];
        uint u2 = ((uint*)&q2)[j], u3 = ((uint*)&q3)[j];
        float lo = w0 * __uint_as_float(u0 << 16) + w1 * __uint_as_float(u1 << 16)
                 + w2 * __uint_as_float(u2 << 16) + w3 * __uint_as_float(u3 << 16);
        float hi = w0 * __uint_as_float(u0 & 0xffff0000u) + w1 * __uint_as_float(u1 & 0xffff0000u)
                 + w2 * __uint_as_float(u2 & 0xffff0000u) + w3 * __uint_as_float(u3 & 0xffff0000u);
        __hip_bfloat16 bl = __float2bfloat16(lo);
        __hip_bfloat16 bh = __float2bfloat16(hi);
        rr[j] = ((uint)*(unsigned short*)&bh << 16) | (uint)*(unsigned short*)&bl;
      }
      uint4 rv = {rr[0], rr[1], rr[2], rr[3]};
      *(uint4*)&S[px * 104 + c8 * 8] = rv;
    }
    __syncthreads();
    // MFMA: A from LDS (S), B direct from global (L1-resident tap slice)
#pragma unroll
    for (int ks = 0; ks < 3; ++ks) {
      int ko = ks * 32 + lg * 8;
      bf16x8 fa0 = *(const bf16x8*)&S[(mw * 32 + lr) * 104 + ko];
      bf16x8 fa1 = *(const bf16x8*)&S[(mw * 32 + 16 + lr) * 104 + ko];
      U8 b0, b1;
      b0.u = *(const uint4*)(wb0 + tap * 96 + ko);
      b1.u = *(const uint4*)(wb1 + tap * 96 + ko);
      a00 = MFMA16(fa0, b0.v, a00);
      a01 = MFMA16(fa0, b1.v, a01);
      a10 = MFMA16(fa1, b0.v, a10);
      a11 = MFMA16(fa1, b1.v, a11);
    }
    // no trailing barrier: next tap writes the OTHER Sa buffer; its barrier
    // guarantees all waves finished this tap's MFMA reads before reuse.
  }
  __syncthreads();

  // bias + leaky into outl[px][oc] (stride 68); outl aliases params region
#pragma unroll
  for (int mi = 0; mi < 2; ++mi)
#pragma unroll
  for (int ni = 0; ni < 2; ++ni) {
    int oc = nw * 32 + ni * 16 + lr;
    float bia = reg_b[oc];
    f32x4 a = (mi == 0) ? (ni == 0 ? a00 : a01) : (ni == 0 ? a10 : a11);
#pragma unroll
    for (int r = 0; r < 4; ++r) {
      int px = mw * 32 + mi * 16 + lg * 4 + r;
      float v = a[r] + bia;
      v = (v >= 0.f) ? v : 0.2f * v;
      outl[px * 68 + oc] = v;
    }
  }
  __syncthreads();

  // channel-LN (64 ch) per px: 4 lanes per px, 16 ch each
  {
    int px = t >> 2, part = t & 3;
    float s = 0.f, s2 = 0.f;
#pragma unroll
    for (int j = 0; j < 16; ++j) {
      float v = outl[px * 68 + part * 16 + j];
      s += v; s2 += v * v;
    }
    s += __shfl_xor(s, 1); s2 += __shfl_xor(s2, 1);
    s += __shfl_xor(s, 2); s2 += __shfl_xor(s2, 2);
    float mu = s * (1.f / 64.f);
    float var = s2 * (1.f / 64.f) - mu * mu;
    float rs = rsqrtf(var + 1e-5f);
    size_t ob = (size_t)b * COUT * 16384 + (size_t)y * 128 + x0 + px;
#pragma unroll
    for (int j = 0; j < 16; ++j) {
      int oc = part * 16 + j;
      float v = outl[px * 68 + oc];
      out[ob + (size_t)oc * 16384] = (v - mu) * rs * lnw[oc] + lnb[oc];
    }
  }
}

extern "C" void kernel_launch(void* const* d_in, const int* in_sizes, int n_in,
                              void* d_out, int out_size, void* d_ws, size_t ws_size,
                              hipStream_t stream) {
  const float* evt      = (const float*)d_in[0];
  const float* efn      = (const float*)d_in[1];
  const float* ln_evt_w = (const float*)d_in[2];
  const float* ln_evt_b = (const float*)d_in[3];
  const float* ln_ef_w  = (const float*)d_in[4];
  const float* ln_ef_b  = (const float*)d_in[5];
  const float* ln_al_w  = (const float*)d_in[6];
  const float* ln_al_b  = (const float*)d_in[7];
  const float* off_w    = (const float*)d_in[8];
  const float* off_b    = (const float*)d_in[9];
  const float* mod_w    = (const float*)d_in[10];
  const float* mod_b    = (const float*)d_in[11];
  const float* reg_w    = (const float*)d_in[12];
  const float* reg_b    = (const float*)d_in[13];
  float* out = (float*)d_out;

  char* wsb = (char*)d_ws;
  __hip_bfloat16* oxb    = (__hip_bfloat16*)wsb;
  float*          offm   = (float*)(wsb + OFFM_OFFB);
  __hip_bfloat16* wcombT = (__hip_bfloat16*)(wsb + WCT_OFFB);
  __hip_bfloat16* wkT    = (__hip_bfloat16*)(wsb + WKT_OFFB);

  prep_weights<<<(32 * 864 + 64 * 864 + 255) / 256, 256, 0, stream>>>(
      off_w, mod_w, reg_w, wcombT, wkT);
  ln_concat<<<BATCH * HH, 128, 0, stream>>>(
      evt, efn, ln_evt_w, ln_evt_b, ln_ef_w, ln_ef_b, oxb);
  conv_offmask_mfma<<<BATCH * HH * WW / 64, 256, 0, stream>>>(
      oxb, wcombT, off_b, mod_b, offm);
  deform_ln_mfma<<<BATCH * HH * WW / 64, 256, 0, stream>>>(
      oxb, offm, wkT, reg_b, ln_al_w, ln_al_b, out);
}

// Round 5
// 174.596 us; speedup vs baseline: 3.0818x; 1.0081x over previous
//
#include <hip/hip_runtime.h>
#include <hip/hip_bf16.h>

#define BATCH 4
#define HH 128
#define WW 128
#define CE 32
#define CF 64
#define CIN 96
#define KK 9
#define COUT 64

typedef __bf16 bf16x8 __attribute__((ext_vector_type(8)));
typedef float f32x4 __attribute__((ext_vector_type(4)));
#define MFMA16(a, b, c) __builtin_amdgcn_mfma_f32_16x16x32_bf16(a, b, c, 0, 0, 0)
typedef union { uint4 u; bf16x8 v; } U8;

// ---- workspace byte offsets ----
#define OX_BYTES   (BATCH * HH * WW * CIN * 2)      // 12,582,912  bf16 NHWC
#define WCT_OFFB   OX_BYTES
#define WCT_BYTES  (32 * 864 * 2)
#define WKT_OFFB   (WCT_OFFB + WCT_BYTES)

// Repack weights to bf16, K-major (k = tap*96 + c), N-transposed.
__global__ void prep_weights(const float* __restrict__ off_w,
                             const float* __restrict__ mod_w,
                             const float* __restrict__ reg_w,
                             __hip_bfloat16* __restrict__ wcombT,
                             __hip_bfloat16* __restrict__ wkT) {
  int e = blockIdx.x * 256 + threadIdx.x;
  const int TOT1 = 32 * 864;
  const int TOT2 = 64 * 864;
  if (e < TOT1) {
    int oc = e / 864, k = e % 864;
    int tap = k / 96, c = k % 96;
    float v = 0.f;
    if (oc < 18)      v = off_w[(oc * CIN + c) * KK + tap];
    else if (oc < 27) v = mod_w[((oc - 18) * CIN + c) * KK + tap];
    wcombT[e] = __float2bfloat16(v);
  } else if (e < TOT1 + TOT2) {
    int e2 = e - TOT1;
    int oc = e2 / 864, k = e2 % 864;
    int tap = k / 96, c = k % 96;
    wkT[e2] = __float2bfloat16(reg_w[(oc * CIN + c) * KK + tap]);
  }
}

// Fused LN(evt)+LN(efnet)+concat -> ox bf16 NHWC. 64 px/block, 256 thr.
__global__ __launch_bounds__(256) void ln_concat(
    const float* __restrict__ evt, const float* __restrict__ efn,
    const float* __restrict__ w_e, const float* __restrict__ b_e,
    const float* __restrict__ w_f, const float* __restrict__ b_f,
    __hip_bfloat16* __restrict__ ox) {
  __shared__ float vals[64 * 97];      // [px][c], stride 97 (conflict-free)
  __shared__ float part[4 * 64 * 4];   // [g][px][{sE,sE2,sF,sF2}]
  __shared__ float stat[64 * 4];       // [px][{muE,rsE,muF,rsF}]

  int bid = blockIdx.x;
  int wg = (bid & 7) * 128 + (bid >> 3);     // XCD-chunked swizzle
  int p0 = wg * 64;
  int b = p0 >> 14, y = (p0 >> 7) & 127, x0 = p0 & 127;
  int t = threadIdx.x, px = t & 63, g = t >> 6;

  float sE = 0.f, sE2 = 0.f, sF = 0.f, sF2 = 0.f;
  const float* pe = evt + (((size_t)b * CE) << 14) + (y << 7) + x0 + px;
#pragma unroll
  for (int j = 0; j < 8; ++j) {
    int c = g * 8 + j;
    float v = pe[(size_t)c << 14];
    vals[px * 97 + c] = v; sE += v; sE2 += v * v;
  }
  const float* pf = efn + (((size_t)b * CF) << 14) + (y << 7) + x0 + px;
#pragma unroll
  for (int j = 0; j < 16; ++j) {
    int c = g * 16 + j;
    float v = pf[(size_t)c << 14];
    vals[px * 97 + CE + c] = v; sF += v; sF2 += v * v;
  }
  {
    float4 p4 = {sE, sE2, sF, sF2};
    *(float4*)&part[(g * 64 + px) * 4] = p4;
  }
  __syncthreads();
  if (g == 0) {
    float aE = 0.f, aE2 = 0.f, aF = 0.f, aF2 = 0.f;
#pragma unroll
    for (int gg = 0; gg < 4; ++gg) {
      float4 p4 = *(const float4*)&part[(gg * 64 + px) * 4];
      aE += p4.x; aE2 += p4.y; aF += p4.z; aF2 += p4.w;
    }
    float muE = aE * (1.f / CE);
    float vE = aE2 * (1.f / CE) - muE * muE;
    float muF = aF * (1.f / CF);
    float vF = aF2 * (1.f / CF) - muF * muF;
    float4 s4 = {muE, rsqrtf(vE + 1e-5f), muF, rsqrtf(vF + 1e-5f)};
    *(float4*)&stat[px * 4] = s4;
  }
  __syncthreads();
  uint* orow = (uint*)(ox + (size_t)p0 * CIN);
#pragma unroll
  for (int i = 0; i < 12; ++i) {               // 3072 uints, coalesced
    int e = i * 256 + t;
    int xx = e / 48, c = (e % 48) * 2;
    float v0 = vals[xx * 97 + c], v1 = vals[xx * 97 + c + 1];
    float mu, rs, lw0, lb0, lw1, lb1;
    if (c < CE) {
      mu = stat[xx * 4 + 0]; rs = stat[xx * 4 + 1];
      lw0 = w_e[c]; lb0 = b_e[c]; lw1 = w_e[c + 1]; lb1 = b_e[c + 1];
    } else {
      mu = stat[xx * 4 + 2]; rs = stat[xx * 4 + 3];
      lw0 = w_f[c - CE]; lb0 = b_f[c - CE]; lw1 = w_f[c + 1 - CE]; lb1 = b_f[c + 1 - CE];
    }
    float o0 = (v0 - mu) * rs * lw0 + lb0;
    float o1 = (v1 - mu) * rs * lw1 + lb1;
    __hip_bfloat16 h0 = __float2bfloat16(o0), h1 = __float2bfloat16(o1);
    orow[e] = ((uint)*(unsigned short*)&h1 << 16) | (uint)*(unsigned short*)&h0;
  }
}

__device__ __forceinline__ uint blend1(uint u0, uint u1, uint u2, uint u3,
                                       float w0, float w1, float w2, float w3) {
  float lo = w0 * __uint_as_float(u0 << 16) + w1 * __uint_as_float(u1 << 16)
           + w2 * __uint_as_float(u2 << 16) + w3 * __uint_as_float(u3 << 16);
  float hi = w0 * __uint_as_float(u0 & 0xffff0000u) + w1 * __uint_as_float(u1 & 0xffff0000u)
           + w2 * __uint_as_float(u2 & 0xffff0000u) + w3 * __uint_as_float(u3 & 0xffff0000u);
  __hip_bfloat16 bl = __float2bfloat16(lo), bh = __float2bfloat16(hi);
  return ((uint)*(unsigned short*)&bh << 16) | (uint)*(unsigned short*)&bl;
}

// Fused: 3x3 conv (27ch offset/mask) -> deform conv -> bias/leaky/LN.
// 64 px per block, 256 thr. Conv: A-band staged once in LDS, B from global.
// Deform: per-thread bilinear params (px = t&63), tap+1 gathers prefetched
// before tap's MFMA (T14), Sa double-buffered, 1 barrier/tap.
__global__ __launch_bounds__(256) void conv_deform_fused(
    const __hip_bfloat16* __restrict__ ox,
    const __hip_bfloat16* __restrict__ wcombT,
    const __hip_bfloat16* __restrict__ wkT,
    const float* __restrict__ off_b, const float* __restrict__ mod_b,
    const float* __restrict__ reg_b,
    const float* __restrict__ lnw, const float* __restrict__ lnb,
    float* __restrict__ out) {
  __shared__ char smem[41216];
  short* At   = (short*)smem;              // [3*66][104] bf16 (conv phase)
  float* offm = (float*)smem;              // [64][28] f32 (aliases At, later)
  short* SaA  = (short*)(smem + 7168);     // [64][104] bf16
  short* SaB  = (short*)(smem + 20480);    // [64][104] bf16
  float* outl = (float*)(smem + 7168);     // [64][68] f32 (epilogue alias)

  int bid = blockIdx.x;
  int wg = (bid & 7) * 128 + (bid >> 3);   // XCD-chunked swizzle
  int p0 = wg * 64;
  int b = p0 >> 14, y = (p0 >> 7) & 127, x0 = p0 & 127;
  const __hip_bfloat16* oxb = ox + (((size_t)b) << 14) * CIN;

  int t = threadIdx.x, lane = t & 63, wv = t >> 6;
  int mw = wv >> 1, nw = wv & 1;
  int lr = lane & 15, lg = lane >> 4;

  // ---- phase A: stage conv A-band (rows y-1..y+1, cols x0-1..x0+64) ----
  for (int u = t; u < 3 * 66 * 12; u += 256) {
    int c8 = u % 12, pw_ = u / 12, w = pw_ % 66, r = pw_ / 66;
    int yy = y + r - 1, xx = x0 + w - 1;
    uint4 v = {0u, 0u, 0u, 0u};
    if ((unsigned)yy < 128u && (unsigned)xx < 128u)
      v = *(const uint4*)(oxb + (size_t)((yy << 7) + xx) * CIN + c8 * 8);
    *(uint4*)&At[(r * 66 + w) * 104 + c8 * 8] = v;
  }
  __syncthreads();

  // ---- phase B: conv matmul (zero inner barriers) ----
  f32x4 cc0 = {0.f,0.f,0.f,0.f}, cc1 = {0.f,0.f,0.f,0.f};
  {
    const __hip_bfloat16* brow = wcombT + (size_t)(nw * 16 + lr) * 864;
#pragma unroll
    for (int tap = 0; tap < 9; ++tap) {
      int dy = tap / 3, dx = tap % 3;
#pragma unroll
      for (int ks = 0; ks < 3; ++ks) {
        int ko = ks * 32 + lg * 8;
        bf16x8 a0 = *(const bf16x8*)&At[(dy * 66 + mw * 32 + lr + dx) * 104 + ko];
        bf16x8 a1 = *(const bf16x8*)&At[(dy * 66 + mw * 32 + 16 + lr + dx) * 104 + ko];
        U8 bf; bf.u = *(const uint4*)(brow + tap * 96 + ko);
        cc0 = MFMA16(a0, bf.v, cc0);
        cc1 = MFMA16(a1, bf.v, cc1);
      }
    }
  }
  __syncthreads();                          // all At reads complete

  {
    int oc = nw * 16 + lr;
    if (oc < 27) {
      float bia = (oc < 18) ? off_b[oc] : mod_b[oc - 18];
#pragma unroll
      for (int mi = 0; mi < 2; ++mi) {
        f32x4 a = mi ? cc1 : cc0;
#pragma unroll
        for (int r = 0; r < 4; ++r) {
          int px2 = mw * 32 + mi * 16 + lg * 4 + r;
          float v = a[r] + bia;
          if (oc >= 18) v = 2.f / (1.f + __expf(-v));
          offm[px2 * 28 + oc] = v;
        }
      }
    }
  }
  __syncthreads();                          // offm ready

  // ---- phase C: deform ----
  int px = t & 63;
  int c8b = wv * 3;
  const __hip_bfloat16* gb = oxb + c8b * 8;
  const __hip_bfloat16* wb0 = wkT + (size_t)(nw * 32 + lr) * 864;
  const __hip_bfloat16* wb1 = wkT + (size_t)(nw * 32 + 16 + lr) * 864;
  f32x4 a00 = {0.f,0.f,0.f,0.f}, a01 = {0.f,0.f,0.f,0.f};
  f32x4 a10 = {0.f,0.f,0.f,0.f}, a11 = {0.f,0.f,0.f,0.f};

  uint4 qa0,qa1,qa2,qa3, qb0,qb1,qb2,qb3, qc0,qc1,qc2,qc3;
  float pw0, pw1, pw2, pw3;

#define ISSUE(TAP)                                                           \
  {                                                                          \
    const float* om = offm + px * 28;                                        \
    float dyv = om[2 * (TAP)], dxv = om[2 * (TAP) + 1], mk = om[18 + (TAP)]; \
    float psy = (float)(y + (TAP) / 3 - 1) + dyv;                            \
    float psx = (float)(x0 + px + (TAP) % 3 - 1) + dxv;                      \
    float fy = floorf(psy), fx = floorf(psx);                                \
    float wy1 = psy - fy, wx1 = psx - fx;                                    \
    float wy0 = 1.f - wy1, wx0 = 1.f - wx1;                                  \
    int iy0 = (int)fy, ix0 = (int)fx, iy1 = iy0 + 1, ix1 = ix0 + 1;          \
    float vy0 = ((unsigned)iy0 < 128u) ? 1.f : 0.f;                          \
    float vy1 = ((unsigned)iy1 < 128u) ? 1.f : 0.f;                          \
    float vx0 = ((unsigned)ix0 < 128u) ? 1.f : 0.f;                          \
    float vx1 = ((unsigned)ix1 < 128u) ? 1.f : 0.f;                          \
    int cy0 = min(max(iy0, 0), 127), cy1 = min(max(iy1, 0), 127);            \
    int cx0 = min(max(ix0, 0), 127), cx1 = min(max(ix1, 0), 127);            \
    int i00 = ((cy0 << 7) + cx0) * CIN, i01 = ((cy0 << 7) + cx1) * CIN;      \
    int i10 = ((cy1 << 7) + cx0) * CIN, i11 = ((cy1 << 7) + cx1) * CIN;      \
    pw0 = wy0 * wx0 * vy0 * vx0 * mk; pw1 = wy0 * wx1 * vy0 * vx1 * mk;      \
    pw2 = wy1 * wx0 * vy1 * vx0 * mk; pw3 = wy1 * wx1 * vy1 * vx1 * mk;      \
    qa0 = *(const uint4*)(gb + i00);      qa1 = *(const uint4*)(gb + i01);   \
    qa2 = *(const uint4*)(gb + i10);      qa3 = *(const uint4*)(gb + i11);   \
    qb0 = *(const uint4*)(gb + i00 + 8);  qb1 = *(const uint4*)(gb + i01 + 8); \
    qb2 = *(const uint4*)(gb + i10 + 8);  qb3 = *(const uint4*)(gb + i11 + 8); \
    qc0 = *(const uint4*)(gb + i00 + 16); qc1 = *(const uint4*)(gb + i01 + 16);\
    qc2 = *(const uint4*)(gb + i10 + 16); qc3 = *(const uint4*)(gb + i11 + 16);\
  }

#define BLEND(Q0, Q1, Q2, Q3, DST)                                           \
  { uint4 rv;                                                                \
    rv.x = blend1(Q0.x, Q1.x, Q2.x, Q3.x, pw0, pw1, pw2, pw3);               \
    rv.y = blend1(Q0.y, Q1.y, Q2.y, Q3.y, pw0, pw1, pw2, pw3);               \
    rv.z = blend1(Q0.z, Q1.z, Q2.z, Q3.z, pw0, pw1, pw2, pw3);               \
    rv.w = blend1(Q0.w, Q1.w, Q2.w, Q3.w, pw0, pw1, pw2, pw3);               \
    *(uint4*)&(DST) = rv; }

  ISSUE(0);
  int buf = 0;
  for (int tap = 0; tap < 9; ++tap) {
    short* S = buf ? SaB : SaA;
    BLEND(qa0, qa1, qa2, qa3, S[px * 104 + (c8b + 0) * 8]);
    BLEND(qb0, qb1, qb2, qb3, S[px * 104 + (c8b + 1) * 8]);
    BLEND(qc0, qc1, qc2, qc3, S[px * 104 + (c8b + 2) * 8]);
    if (tap < 8) ISSUE(tap + 1);            // prefetch next tap's gathers
    __syncthreads();                        // Sa[buf] ready
#pragma unroll
    for (int ks = 0; ks < 3; ++ks) {
      int ko = ks * 32 + lg * 8;
      bf16x8 fa0 = *(const bf16x8*)&S[(mw * 32 + lr) * 104 + ko];
      bf16x8 fa1 = *(const bf16x8*)&S[(mw * 32 + 16 + lr) * 104 + ko];
      U8 b0, b1;
      b0.u = *(const uint4*)(wb0 + tap * 96 + ko);
      b1.u = *(const uint4*)(wb1 + tap * 96 + ko);
      a00 = MFMA16(fa0, b0.v, a00);
      a01 = MFMA16(fa0, b1.v, a01);
      a10 = MFMA16(fa1, b0.v, a10);
      a11 = MFMA16(fa1, b1.v, a11);
    }
    buf ^= 1;
    // single barrier/tap: next write goes to the other Sa buffer; its
    // barrier orders reuse of this one.
  }
  __syncthreads();                          // all Sa reads done

  // ---- epilogue: bias + leaky -> outl, then channel-LN + store ----
#pragma unroll
  for (int mi = 0; mi < 2; ++mi)
#pragma unroll
  for (int ni = 0; ni < 2; ++ni) {
    int oc = nw * 32 + ni * 16 + lr;
    float bia = reg_b[oc];
    f32x4 a = (mi == 0) ? (ni == 0 ? a00 : a01) : (ni == 0 ? a10 : a11);
#pragma unroll
    for (int r = 0; r < 4; ++r) {
      int px2 = mw * 32 + mi * 16 + lg * 4 + r;
      float v = a[r] + bia;
      v = (v >= 0.f) ? v : 0.2f * v;
      outl[px2 * 68 + oc] = v;
    }
  }
  __syncthreads();
  {
    int px2 = t >> 2, part = t & 3;
    float s = 0.f, s2 = 0.f;
#pragma unroll
    for (int j = 0; j < 16; ++j) {
      float v = outl[px2 * 68 + part * 16 + j];
      s += v; s2 += v * v;
    }
    s += __shfl_xor(s, 1); s2 += __shfl_xor(s2, 1);
    s += __shfl_xor(s, 2); s2 += __shfl_xor(s2, 2);
    float mu = s * (1.f / 64.f);
    float var = s2 * (1.f / 64.f) - mu * mu;
    float rs = rsqrtf(var + 1e-5f);
    size_t ob = (size_t)b * COUT * 16384 + (size_t)y * 128 + x0 + px2;
#pragma unroll
    for (int j = 0; j < 16; ++j) {
      int oc = part * 16 + j;
      float v = outl[px2 * 68 + oc];
      out[ob + (size_t)oc * 16384] = (v - mu) * rs * lnw[oc] + lnb[oc];
    }
  }
#undef ISSUE
#undef BLEND
}

extern "C" void kernel_launch(void* const* d_in, const int* in_sizes, int n_in,
                              void* d_out, int out_size, void* d_ws, size_t ws_size,
                              hipStream_t stream) {
  const float* evt      = (const float*)d_in[0];
  const float* efn      = (const float*)d_in[1];
  const float* ln_evt_w = (const float*)d_in[2];
  const float* ln_evt_b = (const float*)d_in[3];
  const float* ln_ef_w  = (const float*)d_in[4];
  const float* ln_ef_b  = (const float*)d_in[5];
  const float* ln_al_w  = (const float*)d_in[6];
  const float* ln_al_b  = (const float*)d_in[7];
  const float* off_w    = (const float*)d_in[8];
  const float* off_b    = (const float*)d_in[9];
  const float* mod_w    = (const float*)d_in[10];
  const float* mod_b    = (const float*)d_in[11];
  const float* reg_w    = (const float*)d_in[12];
  const float* reg_b    = (const float*)d_in[13];
  float* out = (float*)d_out;

  char* wsb = (char*)d_ws;
  __hip_bfloat16* oxb    = (__hip_bfloat16*)wsb;
  __hip_bfloat16* wcombT = (__hip_bfloat16*)(wsb + WCT_OFFB);
  __hip_bfloat16* wkT    = (__hip_bfloat16*)(wsb + WKT_OFFB);

  prep_weights<<<(32 * 864 + 64 * 864 + 255) / 256, 256, 0, stream>>>(
      off_w, mod_w, reg_w, wcombT, wkT);
  ln_concat<<<BATCH * HH * WW / 64, 256, 0, stream>>>(
      evt, efn, ln_evt_w, ln_evt_b, ln_ef_w, ln_ef_b, oxb);
  conv_deform_fused<<<BATCH * HH * WW / 64, 256, 0, stream>>>(
      oxb, wcombT, wkT, off_b, mod_b, reg_b, ln_al_w, ln_al_b, out);
}